// Round 7
// baseline (294.489 us; speedup 1.0000x reference)
//
#include <hip/hip_runtime.h>

// CosineAttention on MI355X (gfx950) — round 7.
// Change vs round 6: flash_attn5 = STATIC-MAX softmax (scores bounded: |qk*T+bias| <= T+1,
// exact for cosine attention) -> no running max, no rescale, no per-iter shfls, no branch;
// P packed via v_cvt_pk_bf16_f32; K LDS fragments hoisted (shared by both Q-frags).
// All other kernels unchanged.

using short4v = __attribute__((ext_vector_type(4))) short;
using short8 = __attribute__((ext_vector_type(8))) short;
using bf16x8 = __attribute__((ext_vector_type(8))) __bf16;
using f32x4  = __attribute__((ext_vector_type(4))) float;
using int4v  = __attribute__((ext_vector_type(4))) int;

constexpr int Bb = 2, Nn = 2048, Cc = 1024, Hh = 16, Dd = 64;

__device__ __forceinline__ unsigned short f2b(float f) {
  unsigned int u = __float_as_uint(f);
  u += 0x7FFFu + ((u >> 16) & 1u);
  return (unsigned short)(u >> 16);
}
__device__ __forceinline__ float b2f(unsigned short h) {
  return __uint_as_float(((unsigned int)h) << 16);
}
__device__ __forceinline__ f32x4 MFMA(short8 a, short8 b, f32x4 c) {
  return __builtin_amdgcn_mfma_f32_16x16x32_bf16(
      __builtin_bit_cast(bf16x8, a), __builtin_bit_cast(bf16x8, b), c, 0, 0, 0);
}
__device__ __forceinline__ unsigned cvtpk(float lo, float hi) {
  unsigned r;
  asm("v_cvt_pk_bf16_f32 %0, %1, %2" : "=v"(r) : "v"(lo), "v"(hi));
  return r;
}

// ---------- split x ----------
__global__ void split_plain(const float* __restrict__ in, unsigned short* __restrict__ hi,
                            unsigned short* __restrict__ lo, int n) {
  int i = blockIdx.x * 256 + threadIdx.x;
  if (i < n) {
    float v = in[i];
    unsigned short t = f2b(v);
    hi[i] = t; lo[i] = f2b(v - b2f(t));
  }
}

// ---------- tiled transpose split: in[K][N] f32 -> hi/lo [N][K] bf16 ----------
__global__ __launch_bounds__(256) void split_trans2(
    const float* __restrict__ in, unsigned short* __restrict__ hi,
    unsigned short* __restrict__ lo, int K, int N) {
  __shared__ float t[32][33];
  int k0 = blockIdx.y * 32, n0 = blockIdx.x * 32;
  int tx = threadIdx.x & 31, ty = threadIdx.x >> 5;
  #pragma unroll
  for (int i = 0; i < 4; i++)
    t[ty + i * 8][tx] = in[(size_t)(k0 + ty + i * 8) * N + n0 + tx];
  __syncthreads();
  #pragma unroll
  for (int i = 0; i < 4; i++) {
    float v = t[tx][ty + i * 8];
    size_t o = (size_t)(n0 + ty + i * 8) * K + k0 + tx;
    unsigned short h = f2b(v);
    hi[o] = h; lo[o] = f2b(v - b2f(h));
  }
}

// ---------- fused 3-term split GEMM (unchanged) ----------
__global__ __launch_bounds__(256, 3) void gemm3(
    const unsigned short* __restrict__ Ah, const unsigned short* __restrict__ Al,
    const unsigned short* __restrict__ Bh, const unsigned short* __restrict__ Bl,
    float* __restrict__ C, int M, int N, int K) {
  __shared__ unsigned short sAh[128][40], sAl[128][40], sBh[128][40], sBl[128][40];
  int tid = threadIdx.x;
  int w = tid >> 6, l = tid & 63;
  int wr = w >> 1, wc = w & 1;
  int mrow = l & 15, kg = l >> 4;
  int row0 = blockIdx.y * 128, col0 = blockIdx.x * 128;
  f32x4 z = {0.f, 0.f, 0.f, 0.f};
  f32x4 acc[4][4];
  for (int i = 0; i < 4; i++) for (int j = 0; j < 4; j++) acc[i][j] = z;
  int sr = tid >> 1, sc0 = (tid & 1) * 16;
  for (int k0 = 0; k0 < K; k0 += 32) {
    const unsigned short* pa = Ah + (size_t)(row0 + sr) * K + k0 + sc0;
    const unsigned short* pal = Al + (size_t)(row0 + sr) * K + k0 + sc0;
    const unsigned short* pb = Bh + (size_t)(col0 + sr) * K + k0 + sc0;
    const unsigned short* pbl = Bl + (size_t)(col0 + sr) * K + k0 + sc0;
    short8 tA0 = *(const short8*)pa,  tA1 = *(const short8*)(pa + 8);
    short8 tL0 = *(const short8*)pal, tL1 = *(const short8*)(pal + 8);
    short8 tB0 = *(const short8*)pb,  tB1 = *(const short8*)(pb + 8);
    short8 tC0 = *(const short8*)pbl, tC1 = *(const short8*)(pbl + 8);
    __syncthreads();
    *(short8*)&sAh[sr][sc0] = tA0; *(short8*)&sAh[sr][sc0 + 8] = tA1;
    *(short8*)&sAl[sr][sc0] = tL0; *(short8*)&sAl[sr][sc0 + 8] = tL1;
    *(short8*)&sBh[sr][sc0] = tB0; *(short8*)&sBh[sr][sc0 + 8] = tB1;
    *(short8*)&sBl[sr][sc0] = tC0; *(short8*)&sBl[sr][sc0 + 8] = tC1;
    __syncthreads();
    short8 ah_[4], al_[4], bh_[4], bl_[4];
    #pragma unroll
    for (int mt = 0; mt < 4; mt++) {
      ah_[mt] = *(const short8*)&sAh[wr * 64 + mt * 16 + mrow][kg * 8];
      al_[mt] = *(const short8*)&sAl[wr * 64 + mt * 16 + mrow][kg * 8];
    }
    #pragma unroll
    for (int nt = 0; nt < 4; nt++) {
      bh_[nt] = *(const short8*)&sBh[wc * 64 + nt * 16 + mrow][kg * 8];
      bl_[nt] = *(const short8*)&sBl[wc * 64 + nt * 16 + mrow][kg * 8];
    }
    __builtin_amdgcn_s_setprio(1);
    #pragma unroll
    for (int mt = 0; mt < 4; mt++)
      #pragma unroll
      for (int nt = 0; nt < 4; nt++) {
        acc[mt][nt] = MFMA(ah_[mt], bh_[nt], acc[mt][nt]);
        acc[mt][nt] = MFMA(al_[mt], bh_[nt], acc[mt][nt]);
        acc[mt][nt] = MFMA(ah_[mt], bl_[nt], acc[mt][nt]);
      }
    __builtin_amdgcn_s_setprio(0);
  }
  #pragma unroll
  for (int mt = 0; mt < 4; mt++)
    #pragma unroll
    for (int nt = 0; nt < 4; nt++)
      #pragma unroll
      for (int q = 0; q < 4; q++) {
        int row = row0 + wr * 64 + mt * 16 + kg * 4 + q;
        int col = col0 + wc * 64 + nt * 16 + mrow;
        C[(size_t)row * N + col] = acc[mt][nt][q];
      }
}

// ---------- qkv deinterleave + l2norm + split (unchanged) ----------
__global__ __launch_bounds__(256) void qkv_post2(
    const float* __restrict__ qkv,
    unsigned short* __restrict__ qh, unsigned short* __restrict__ ql,
    unsigned short* __restrict__ kh, unsigned short* __restrict__ kl,
    unsigned short* __restrict__ vth) {
  __shared__ unsigned short vt[64][72];
  int tid = threadIdx.x, w = tid >> 6, d = tid & 63;
  int bid = blockIdx.x;
  int nb = bid & 31, h = (bid >> 5) & 15, b = bid >> 9;
  size_t head = (size_t)(b * Hh + h);
  int n0 = nb * 64;
  for (int it = 0; it < 16; it++) {
    int nl = w * 16 + it;
    int n = n0 + nl;
    const float* src = qkv + (size_t)(b * Nn + n) * 3072 + h * 192 + d * 3;
    float qv = src[0], kv = src[1], vv = src[2];
    float q2 = qv * qv, k2 = kv * kv;
    #pragma unroll
    for (int m = 1; m < 64; m <<= 1) { q2 += __shfl_xor(q2, m); k2 += __shfl_xor(k2, m); }
    qv /= fmaxf(sqrtf(q2), 1e-12f);
    kv /= fmaxf(sqrtf(k2), 1e-12f);
    size_t o = (head * Nn + n) * Dd + d;
    unsigned short tq = f2b(qv); qh[o] = tq; ql[o] = f2b(qv - b2f(tq));
    unsigned short tk = f2b(kv); kh[o] = tk; kl[o] = f2b(kv - b2f(tk));
    vt[nl][d] = f2b(vv);
  }
  __syncthreads();
  int r = tid >> 2, cq = (tid & 3) * 16;
  short8 x0, x1;
  #pragma unroll
  for (int i = 0; i < 8; i++) ((short*)&x0)[i] = (short)vt[cq + i][r];
  #pragma unroll
  for (int i = 0; i < 8; i++) ((short*)&x1)[i] = (short)vt[cq + 8 + i][r];
  unsigned short* dst = vth + (head * Dd + r) * Nn + n0 + cq;
  *(short8*)dst = x0;
  *(short8*)(dst + 8) = x1;
}

// ---------- flash attention: static-max softmax, shared K frags, ping-pong LDS ----------
// Scores bounded: |s*T| <= T (unit q,k), |bias| < 1  ->  static max Ms = T+1.
// P = exp2(s*T*log2e + (bias - Ms)*log2e): lane-local, no shfl/branch/rescale per iter.
// L merged across kg once at the end (2 shfls per frag per kernel).
__global__ __launch_bounds__(256, 2) void flash_attn5(
    const unsigned short* __restrict__ qh_g, const unsigned short* __restrict__ ql_g,
    const unsigned short* __restrict__ kh_g, const unsigned short* __restrict__ kl_g,
    const unsigned short* __restrict__ vh_g,
    const float* __restrict__ bias, const float* __restrict__ tptr,
    unsigned short* __restrict__ ah, unsigned short* __restrict__ al) {
  __shared__ unsigned short sKh[2][64][64], sKl[2][64][64], sVh[2][64][64];
  int tid = threadIdx.x, w = tid >> 6, l = tid & 63;
  int mrow = l & 15, kg = l >> 4;
  int bid = blockIdx.x;
  int b = bid & 1, h = (bid >> 1) & 15, ib = bid >> 5;   // ib in [0,16)
  float T = tptr[0];
  const float L2E = 1.44269504f;
  float Tl2 = T * L2E;
  float negMs = -(T + 1.0f) * L2E;                       // static-max offset (log2 domain)
  size_t head = (size_t)(b * Hh + h);
  int i0 = ib * 128 + w * 32;
  short8 aqh0[2], aql0[2], aqh1[2], aql1[2];
  {
    size_t qb0 = (head * Nn + i0 + mrow) * Dd;
    size_t qb1 = (head * Nn + i0 + 16 + mrow) * Dd;
    #pragma unroll
    for (int kk = 0; kk < 2; kk++) {
      aqh0[kk] = *(const short8*)(qh_g + qb0 + kk * 32 + kg * 8);
      aql0[kk] = *(const short8*)(ql_g + qb0 + kk * 32 + kg * 8);
      aqh1[kk] = *(const short8*)(qh_g + qb1 + kk * 32 + kg * 8);
      aql1[kk] = *(const short8*)(ql_g + qb1 + kk * 32 + kg * 8);
    }
  }
  f32x4 Ot0[4], Ot1[4];
  #pragma unroll
  for (int dt = 0; dt < 4; dt++) { Ot0[dt] = {0.f,0.f,0.f,0.f}; Ot1[dt] = {0.f,0.f,0.f,0.f}; }
  float L0 = 0.f, L1 = 0.f;

  int r0 = tid >> 3, c0 = (tid & 7) * 8;
  int r1 = r0 + 32;
  int lk0 = r0 * 64 + (c0 ^ ((r0 & 7) << 3));
  int lk1 = r1 * 64 + (c0 ^ ((r1 & 7) << 3));
  int pr0 = (r0 & 32) | ((r0 & 12) << 1) | ((r0 & 16) >> 2) | (r0 & 3);
  int pr1 = (r1 & 32) | ((r1 & 12) << 1) | ((r1 & 16) >> 2) | (r1 & 3);
  const unsigned short* kh_b = kh_g + head * Nn * Dd;
  const unsigned short* kl_b = kl_g + head * Nn * Dd;
  const unsigned short* vh_b = vh_g + head * Dd * Nn;
  const float* bbA = bias + ((size_t)h * Nn + i0 + mrow) * Nn + kg * 8;
  const float* bbB = bbA + (size_t)16 * Nn;

  short8 rKh0, rKh1, rKl0, rKl1, rVh0, rVh1;
  f32x4 rB0[4], rB1[4];

  auto issueKV = [&](int j0) {
    rKh0 = *(const short8*)(kh_b + (size_t)(j0 + pr0) * Dd + c0);
    rKh1 = *(const short8*)(kh_b + (size_t)(j0 + pr1) * Dd + c0);
    rKl0 = *(const short8*)(kl_b + (size_t)(j0 + pr0) * Dd + c0);
    rKl1 = *(const short8*)(kl_b + (size_t)(j0 + pr1) * Dd + c0);
    rVh0 = *(const short8*)(vh_b + (size_t)r0 * Nn + j0 + c0);
    rVh1 = *(const short8*)(vh_b + (size_t)r1 * Nn + j0 + c0);
  };
  auto writeKV = [&](int dst) {
    *(short8*)((unsigned short*)sKh[dst] + lk0) = rKh0;
    *(short8*)((unsigned short*)sKh[dst] + lk1) = rKh1;
    *(short8*)((unsigned short*)sKl[dst] + lk0) = rKl0;
    *(short8*)((unsigned short*)sKl[dst] + lk1) = rKl1;
    *(short8*)((unsigned short*)sVh[dst] + lk0) = rVh0;
    *(short8*)((unsigned short*)sVh[dst] + lk1) = rVh1;
  };
  auto issueBias = [&](int j0) {
    rB0[0] = *(const f32x4*)(bbA + j0);
    rB0[1] = *(const f32x4*)(bbA + j0 + 4);
    rB0[2] = *(const f32x4*)(bbA + j0 + 32);
    rB0[3] = *(const f32x4*)(bbA + j0 + 36);
    rB1[0] = *(const f32x4*)(bbB + j0);
    rB1[1] = *(const f32x4*)(bbB + j0 + 4);
    rB1[2] = *(const f32x4*)(bbB + j0 + 32);
    rB1[3] = *(const f32x4*)(bbB + j0 + 36);
    #pragma unroll
    for (int i = 0; i < 4; i++) {       // fold (bias - Ms)*log2e once, off the hot chain
      rB0[i] = rB0[i] * L2E + negMs;
      rB1[i] = rB1[i] * L2E + negMs;
    }
  };
  // static-max softmax: pure lane-local, no shfl, no branch
  auto softmax = [&](f32x4* s, f32x4* rB, float& L_, short8& pf0, short8& pf1) {
    float p_[4][4];
    float ps = 0.f;
    #pragma unroll
    for (int jt = 0; jt < 4; jt++)
      #pragma unroll
      for (int q = 0; q < 4; q++) {
        p_[jt][q] = __builtin_amdgcn_exp2f(fmaf(s[jt][q], Tl2, rB[jt][q]));
        ps += p_[jt][q];
      }
    L_ += ps;
    unsigned pk[8];
    #pragma unroll
    for (int jt = 0; jt < 4; jt++) {
      pk[2 * jt]     = cvtpk(p_[jt][0], p_[jt][1]);
      pk[2 * jt + 1] = cvtpk(p_[jt][2], p_[jt][3]);
    }
    int4v w0 = {(int)pk[0], (int)pk[1], (int)pk[2], (int)pk[3]};
    int4v w1 = {(int)pk[4], (int)pk[5], (int)pk[6], (int)pk[7]};
    pf0 = __builtin_bit_cast(short8, w0);
    pf1 = __builtin_bit_cast(short8, w1);
  };

  issueKV(0);
  issueBias(0);
  writeKV(0);
  __syncthreads();
  issueKV(64);

  for (int t = 0; t < 32; t++) {
    int j0 = t * 64;
    int cur = t & 1;
    // QK^T both frags, K fragments read once and shared
    f32x4 s0[4], s1[4];
    #pragma unroll
    for (int jt = 0; jt < 4; jt++) { s0[jt] = {0.f,0.f,0.f,0.f}; s1[jt] = {0.f,0.f,0.f,0.f}; }
    __builtin_amdgcn_s_setprio(1);
    #pragma unroll
    for (int jt = 0; jt < 4; jt++) {
      int row = jt * 16 + mrow;
      int swz = (row & 7) << 3;
      #pragma unroll
      for (int kk = 0; kk < 2; kk++) {
        short8 bh = *(const short8*)&sKh[cur][row][(kk * 32 + kg * 8) ^ swz];
        short8 bl = *(const short8*)&sKl[cur][row][(kk * 32 + kg * 8) ^ swz];
        s0[jt] = MFMA(bh, aqh0[kk], s0[jt]);
        s0[jt] = MFMA(bh, aql0[kk], s0[jt]);
        s0[jt] = MFMA(bl, aqh0[kk], s0[jt]);
        s1[jt] = MFMA(bh, aqh1[kk], s1[jt]);
        s1[jt] = MFMA(bh, aql1[kk], s1[jt]);
        s1[jt] = MFMA(bl, aqh1[kk], s1[jt]);
      }
    }
    __builtin_amdgcn_s_setprio(0);
    short8 pfA0, pfA1, pfB0, pfB1;
    softmax(s0, rB0, L0, pfA0, pfA1);
    softmax(s1, rB1, L1, pfB0, pfB1);
    if (t < 31) issueBias(j0 + 64);
    if (t < 31) writeKV(cur ^ 1);
    if (t < 30) issueKV(j0 + 128);
    __builtin_amdgcn_s_setprio(1);
    #pragma unroll
    for (int dt = 0; dt < 4; dt++) {
      int row = dt * 16 + mrow;
      int swz = (row & 7) << 3;
      short8 va0 = *(const short8*)&sVh[cur][row][(kg * 8) ^ swz];
      short8 va1 = *(const short8*)&sVh[cur][row][(32 + kg * 8) ^ swz];
      Ot0[dt] = MFMA(va0, pfA0, Ot0[dt]);
      Ot0[dt] = MFMA(va1, pfA1, Ot0[dt]);
      Ot1[dt] = MFMA(va0, pfB0, Ot1[dt]);
      Ot1[dt] = MFMA(va1, pfB1, Ot1[dt]);
    }
    __builtin_amdgcn_s_setprio(0);
    __syncthreads();
  }
  // merge L across the 4 kg groups (disjoint key sets), once
  L0 += __shfl_xor(L0, 16); L0 += __shfl_xor(L0, 32);
  L1 += __shfl_xor(L1, 16); L1 += __shfl_xor(L1, 32);
  float inv0 = 1.f / L0, inv1 = 1.f / L1;
  size_t orow0 = ((size_t)(b * Nn + i0 + mrow)) * (Hh * Dd) + h * Dd + kg * 4;
  size_t orow1 = ((size_t)(b * Nn + i0 + 16 + mrow)) * (Hh * Dd) + h * Dd + kg * 4;
  #pragma unroll
  for (int dt = 0; dt < 4; dt++) {
    short4v hi4, lo4;
    #pragma unroll
    for (int r = 0; r < 4; r++) {
      float val = Ot0[dt][r] * inv0;
      unsigned short hv = f2b(val);
      hi4[r] = (short)hv;
      lo4[r] = (short)f2b(val - b2f(hv));
    }
    *(short4v*)(ah + orow0 + dt * 16) = hi4;
    *(short4v*)(al + orow0 + dt * 16) = lo4;
    #pragma unroll
    for (int r = 0; r < 4; r++) {
      float val = Ot1[dt][r] * inv1;
      unsigned short hv = f2b(val);
      hi4[r] = (short)hv;
      lo4[r] = (short)f2b(val - b2f(hv));
    }
    *(short4v*)(ah + orow1 + dt * 16) = hi4;
    *(short4v*)(al + orow1 + dt * 16) = lo4;
  }
}

extern "C" void kernel_launch(void* const* d_in, const int* in_sizes, int n_in,
                              void* d_out, int out_size, void* d_ws, size_t ws_size,
                              hipStream_t stream) {
  const float* x    = (const float*)d_in[0];
  const float* Wqkv = (const float*)d_in[1];
  const float* Wout = (const float*)d_in[2];
  const float* temp = (const float*)d_in[3];
  const float* bias = (const float*)d_in[4];
  float* out = (float*)d_out;

  char* ws = (char*)d_ws;
  size_t off = 0;
  auto alloc = [&](size_t bytes) -> void* {
    void* p = ws + off;
    off += (bytes + 255) & ~(size_t)255;
    return p;
  };
  const size_t MT = (size_t)Bb * Nn;
  float* qkv = (float*)alloc(MT * 3072 * 4);
  unsigned short* xh  = (unsigned short*)alloc(MT * Cc * 2);
  unsigned short* xl  = (unsigned short*)alloc(MT * Cc * 2);
  unsigned short* wqh = (unsigned short*)alloc((size_t)3072 * Cc * 2);
  unsigned short* wql = (unsigned short*)alloc((size_t)3072 * Cc * 2);
  unsigned short* woh = (unsigned short*)alloc((size_t)Cc * Cc * 2);
  unsigned short* wol = (unsigned short*)alloc((size_t)Cc * Cc * 2);
  const size_t HND = (size_t)Bb * Hh * Nn * Dd;
  unsigned short* qh  = (unsigned short*)alloc(HND * 2);
  unsigned short* ql  = (unsigned short*)alloc(HND * 2);
  unsigned short* kh  = (unsigned short*)alloc(HND * 2);
  unsigned short* kl  = (unsigned short*)alloc(HND * 2);
  unsigned short* vth = (unsigned short*)alloc(HND * 2);
  unsigned short* ah  = (unsigned short*)alloc(MT * Cc * 2);
  unsigned short* al  = (unsigned short*)alloc(MT * Cc * 2);
  (void)ws_size; (void)in_sizes; (void)n_in; (void)out_size;

  split_plain<<<dim3((int)(MT * Cc / 256)), dim3(256), 0, stream>>>(x, xh, xl, (int)(MT * Cc));
  split_trans2<<<dim3(3072 / 32, Cc / 32), dim3(256), 0, stream>>>(Wqkv, wqh, wql, Cc, 3072);
  split_trans2<<<dim3(Cc / 32, Cc / 32), dim3(256), 0, stream>>>(Wout, woh, wol, Cc, Cc);

  gemm3<<<dim3(3072 / 128, (int)(MT / 128)), dim3(256), 0, stream>>>(
      xh, xl, wqh, wql, qkv, (int)MT, 3072, Cc);

  qkv_post2<<<dim3(Bb * Hh * (Nn / 64)), dim3(256), 0, stream>>>(
      qkv, qh, ql, kh, kl, vth);

  flash_attn5<<<dim3(Bb * Hh * (Nn / 128)), dim3(256), 0, stream>>>(
      qh, ql, kh, kl, vth, bias, temp, ah, al);

  gemm3<<<dim3(Cc / 128, (int)(MT / 128)), dim3(256), 0, stream>>>(
      ah, al, woh, wol, out, (int)MT, Cc, Cc);
}